// Round 11
// baseline (65.639 us; speedup 1.0000x reference)
//
#include <hip/hip_runtime.h>
#include <math.h>

#define NPTS   8192
#define BITS   64
#define NCLS   101
#define TILE   128
#define NT     (NPTS / TILE)            // 64
#define NPAIRS (NT * (NT + 1) / 2)      // 2080
#define NCLSB  2048                     // blocks carrying cls rows (4 each)
#define SCALE  0.84932184f              // sqrt(0.5*log2 e): acc = t = theta*log2(e)
#define LN2    0.6931471805599453
#define SCH_BITS 1064872494             // (127<<23) - 0.0573*2^23 (mean-zero Schraudolph)

// ws layout (bytes):
#define OFF_RANK 0u                       // int[8192]
#define OFF_BASE 32768u                   // int[102] class prefix (base[101]=8192)
#define OFF_HB   33280u                   // bf16[8192*64] class-sorted, scaled (1MB)
#define OFF_SAO  (OFF_HB + 1048576u)      // double[2080] pass-A off-diag partials
#define OFF_SAD  (OFF_SAO + 16640u)       // double[2080] pass-A diag-tile partials
#define OFF_CLS  (OFF_SAD + 16640u)       // double[2048] cls partials
#define OFF_BSP  (OFF_CLS + 16384u)       // double[101]  pass-B sp sums (full blocks)
#define OFF_BT   (OFF_BSP + 1024u)        // double[101]  pass-B t sums
#define OFF_D    (OFF_BT + 1024u)         // double[64*2] {Dsp, Dt} per scatter block

typedef short    bf16x8   __attribute__((ext_vector_type(8)));
typedef unsigned short ushort8v __attribute__((ext_vector_type(8)));
typedef float    f32x16   __attribute__((ext_vector_type(16)));

__device__ __forceinline__ unsigned short f2bf(float f) {
    unsigned int u = __float_as_uint(f);
    u += 0x7FFFu + ((u >> 16) & 1u);     // RNE (inputs finite)
    return (unsigned short)(u >> 16);
}
__device__ __forceinline__ float bf2f(unsigned short u) {
    return __uint_as_float((unsigned int)u << 16);
}
__device__ __forceinline__ float flog2(float x) {
    float r; asm("v_log_f32 %0, %1" : "=v"(r) : "v"(x)); return r;
}
__device__ __forceinline__ float exp2_fast(float v) {   // v <= 0, > -126
    int ib = (int)(v * 8388608.0f);
    return __int_as_float(ib + SCH_BITS);
}
__device__ __forceinline__ void tile_map(int p, int& ti, int& tj) {
    float disc = (2.0f * NT + 1.0f) * (2.0f * NT + 1.0f) - 8.0f * (float)p;
    ti = (int)(((2.0f * NT + 1.0f) - sqrtf(disc)) * 0.5f);
    if (ti < 0) ti = 0;
    if (ti >= NT) ti = NT - 1;
    while (ti > 0 && (ti * NT - ti * (ti - 1) / 2) > p) ti--;
    while ((ti + 1) * NT - (ti + 1) * ti / 2 <= p) ti++;
    tj = ti + (p - (ti * NT - ti * (ti - 1) / 2));
}

// ---------------------------------------------------------------------------
// K1: deterministic stable class-rank. Each block recomputes hist+prefix;
// wave w of block b ranks class 4b+w via 64-lane ballot scan. No atomics
// across kernels; fully deterministic.
// ---------------------------------------------------------------------------
__global__ __launch_bounds__(256) void rank_kernel(const int* __restrict__ tgt,
                                                   int* __restrict__ rank,
                                                   int* __restrict__ base) {
    __shared__ int hist[NCLS];
    __shared__ int pbase[NCLS + 1];
    const int tid = threadIdx.x, lane = tid & 63, wave = tid >> 6;

    for (int i = tid; i < NCLS; i += 256) hist[i] = 0;
    __syncthreads();
    for (int i = tid; i < NPTS; i += 256) atomicAdd(&hist[tgt[i]], 1);
    __syncthreads();
    if (tid == 0) {
        int run = 0;
        for (int c = 0; c < NCLS; ++c) { pbase[c] = run; run += hist[c]; }
        pbase[NCLS] = run;
    }
    __syncthreads();

    const int c = blockIdx.x * 4 + wave;
    if (c < NCLS) {
        int running = pbase[c];
        for (int k = 0; k < NPTS / 64; ++k) {
            const int v = tgt[k * 64 + lane];
            const bool m = (v == c);
            const unsigned long long bm = __ballot(m);
            if (m)
                rank[k * 64 + lane] =
                    running + (int)__popcll(bm & ((1ull << lane) - 1ull));
            running += (int)__popcll(bm);
        }
    }
    if (blockIdx.x == 0 && tid <= NCLS) base[tid] = pbase[tid];
}

// ---------------------------------------------------------------------------
// K2: scatter rows into class-sorted bf16 (scaled) + diagonal sums D.
// 64 blocks x 128 rows. Also computes per-block {Dsp, Dt} from the SAME
// bf16-rounded values the MFMA consumes.
// ---------------------------------------------------------------------------
__global__ __launch_bounds__(256) void scatter_kernel(const float* __restrict__ H,
                                                      const int* __restrict__ rank,
                                                      unsigned short* __restrict__ Hb,
                                                      double* __restrict__ wsD) {
    __shared__ int rk[128];
    __shared__ double redd[4];
    const int tid = threadIdx.x, lane = tid & 63, wave = tid >> 6;
    const int r0 = blockIdx.x * 128;

    if (tid < 128) rk[tid] = rank[r0 + tid];
    __syncthreads();
#pragma unroll
    for (int it = 0; it < 4; ++it) {          // 1024 tasks: row(0..127) x 8-col chunk
        const int idx = tid + it * 256;
        const int row = idx >> 3, c8 = idx & 7;
        const float* src = H + (size_t)(r0 + row) * BITS + c8 * 8;
        float4 f0 = *(const float4*)src;
        float4 f1 = *(const float4*)(src + 4);
        ushort8v v;
        v[0] = f2bf(f0.x * SCALE); v[1] = f2bf(f0.y * SCALE);
        v[2] = f2bf(f0.z * SCALE); v[3] = f2bf(f0.w * SCALE);
        v[4] = f2bf(f1.x * SCALE); v[5] = f2bf(f1.y * SCALE);
        v[6] = f2bf(f1.z * SCALE); v[7] = f2bf(f1.w * SCALE);
        *(ushort8v*)(Hb + (size_t)rk[row] * BITS + c8 * 8) = v;
    }

    // diagonal: t_ii = sum_k bf16(h*SCALE)^2 (fp32 accumulate), sp-consistent
    float dsp = 0.f, dt = 0.f;
    if (tid < 128) {
        float t = 0.f;
        const float* src = H + (size_t)(r0 + tid) * BITS;
#pragma unroll
        for (int k = 0; k < BITS; ++k) {
            float f = bf2f(f2bf(src[k] * SCALE));
            t = fmaf(f, f, t);
        }
        float u = exp2_fast(0.f - t);          // t >= 0
        dsp = t + flog2(1.f + u);
        dt  = t;
    }
#pragma unroll
    for (int d = 32; d > 0; d >>= 1) {
        dsp += __shfl_xor(dsp, d, 64);
        dt  += __shfl_xor(dt,  d, 64);
    }
    if (lane == 0 && wave < 2) { redd[wave] = (double)dsp; redd[2 + wave] = (double)dt; }
    __syncthreads();
    if (tid == 0) {
        wsD[blockIdx.x * 2 + 0] = redd[0] + redd[1];
        wsD[blockIdx.x * 2 + 1] = redd[2] + redd[3];
    }
}

// ---------------------------------------------------------------------------
// K3: pass A (p < NPAIRS): maskless 128x128 tiles over sorted Hb, direct
// global fragment loads, 8-op epilogue, full-square diag tiles (corrected in
// finalize). cls rows ride on p < 2048. pass B (p >= NPAIRS): per-class
// full-block same-class sums with boundary masks.
// ---------------------------------------------------------------------------
__global__ __launch_bounds__(256) void pass_kernel(const unsigned short* __restrict__ HB,
                                                   const float* __restrict__ X,
                                                   const int* __restrict__ tgt,
                                                   const int* __restrict__ base,
                                                   double* __restrict__ ws) {
    __shared__ float red[16];
    double* wsAo = (double*)((char*)ws + (OFF_SAO - OFF_SAO));   // alias helpers below
    const int tid = threadIdx.x, lane = tid & 63, wave = tid >> 6;
    const int lrow = lane & 31, hi = lane >> 5;
    const int p = blockIdx.x;

    double* A_off = (double*)((char*)ws);                         // [0,2080)
    double* A_dia = (double*)((char*)ws + 16640u);                // [2080)
    double* C_cls = (double*)((char*)ws + 33280u);                // [2048)
    double* B_sp  = (double*)((char*)ws + 49664u);                // [101]
    double* B_t   = (double*)((char*)ws + 50688u);                // [101]
    (void)wsAo;

    if (p < NPAIRS) {
        // ---------------- pass A ----------------
        int ti, tj; tile_map(p, ti, tj);
        const int i0 = ti * TILE, j0 = tj * TILE;
        const bool diag = (ti == tj);
        const int wr = wave >> 1, wc = wave & 1;

        const ushort8v* pA0 = (const ushort8v*)(HB + (size_t)(i0 + wr * 64 +      lrow) * BITS + hi * 8);
        const ushort8v* pA1 = (const ushort8v*)(HB + (size_t)(i0 + wr * 64 + 32 + lrow) * BITS + hi * 8);
        const ushort8v* pB0 = (const ushort8v*)(HB + (size_t)(j0 + wc * 64 +      lrow) * BITS + hi * 8);
        const ushort8v* pB1 = (const ushort8v*)(HB + (size_t)(j0 + wc * 64 + 32 + lrow) * BITS + hi * 8);

        bf16x8 fa0[4], fa1[4], fb0[4], fb1[4];
#pragma unroll
        for (int ks = 0; ks < 4; ++ks) {
            fa0[ks] = __builtin_bit_cast(bf16x8, pA0[ks * 2]);
            fa1[ks] = __builtin_bit_cast(bf16x8, pA1[ks * 2]);
            fb0[ks] = __builtin_bit_cast(bf16x8, pB0[ks * 2]);
            fb1[ks] = __builtin_bit_cast(bf16x8, pB1[ks * 2]);
        }

        f32x16 c00, c01, c10, c11;
#pragma unroll
        for (int e = 0; e < 16; ++e) { c00[e] = 0.f; c01[e] = 0.f; c10[e] = 0.f; c11[e] = 0.f; }
#pragma unroll
        for (int ks = 0; ks < 4; ++ks) {
            c00 = __builtin_amdgcn_mfma_f32_32x32x16_bf16(fa0[ks], fb0[ks], c00, 0, 0, 0);
            c01 = __builtin_amdgcn_mfma_f32_32x32x16_bf16(fa0[ks], fb1[ks], c01, 0, 0, 0);
            c10 = __builtin_amdgcn_mfma_f32_32x32x16_bf16(fa1[ks], fb0[ks], c10, 0, 0, 0);
            c11 = __builtin_amdgcn_mfma_f32_32x32x16_bf16(fa1[ks], fb1[ks], c11, 0, 0, 0);
        }

        // maskless 8-op epilogue: prod of (1+2^-|t|), sums of t and |t|
        float prod = 1.f, st = 0.f, sa = 0.f;
#pragma unroll
        for (int q = 0; q < 4; ++q) {
            const f32x16& C = q == 0 ? c00 : (q == 1 ? c01 : (q == 2 ? c10 : c11));
#pragma unroll
            for (int r = 0; r < 16; ++r) {
                float t = C[r];
                float u = exp2_fast(fminf(t, 0.f - t));   // 2^{-|t|}
                prod *= (1.0f + u);
                st += t;
                sa += fabsf(t);
            }
        }
        float s = fmaf(st + sa, 0.5f, flog2(prod));
#pragma unroll
        for (int d = 32; d > 0; d >>= 1) s += __shfl_xor(s, d, 64);
        if (lane == 0) red[wave] = s;

        {   // fused cls rows on p < 2048
            float nll = 0.f;
            const int row = p * 4 + wave;
            if (p < NCLSB) {
                const float* x = X + (size_t)row * NCLS;
                float x1 = x[lane];
                float x2 = (lane + 64 < NCLS) ? x[lane + 64] : -INFINITY;
                float m = fmaxf(x1, x2);
#pragma unroll
                for (int d = 32; d > 0; d >>= 1) m = fmaxf(m, __shfl_xor(m, d, 64));
                float e = __expf(x1 - m) + ((lane + 64 < NCLS) ? __expf(x2 - m) : 0.f);
#pragma unroll
                for (int d = 32; d > 0; d >>= 1) e += __shfl_xor(e, d, 64);
                if (lane == 0) nll = m + __logf(e) - x[tgt[row]];
            }
            if (lane == 0) red[4 + wave] = nll;
        }
        __syncthreads();
        if (tid == 0) {
            double sv = (double)red[0] + (double)red[1] + (double)red[2] + (double)red[3];
            A_off[p] = diag ? 0.0 : sv;
            A_dia[p] = diag ? sv : 0.0;
            if (p < NCLSB)
                C_cls[p] = (double)red[4] + (double)red[5] + (double)red[6] + (double)red[7];
        }
    } else {
        // ---------------- pass B: class q full-block sums ----------------
        const int q = p - NPAIRS;
        const int b = base[q], n = base[q + 1] - b;
        const int S = (n + 31) >> 5;

        float prod = 1.f, st = 0.f, sa = 0.f;
        for (int sst = wave; sst < S; sst += 4) {
            const int arow = b + sst * 32 + lrow;
            const ushort8v* pA = (const ushort8v*)(HB + (size_t)min(arow, NPTS - 1) * BITS + hi * 8);
            bf16x8 fa[4];
#pragma unroll
            for (int ks = 0; ks < 4; ++ks) fa[ks] = __builtin_bit_cast(bf16x8, pA[ks * 2]);

            bool row_ok[16];
#pragma unroll
            for (int r = 0; r < 16; ++r)
                row_ok[r] = (sst * 32 + (r & 3) + 8 * (r >> 2) + 4 * hi) < n;

            for (int ct = 0; ct < S; ++ct) {
                const int brow = b + ct * 32 + lrow;
                const bool col_ok = (ct * 32 + lrow) < n;
                const ushort8v* pB = (const ushort8v*)(HB + (size_t)min(brow, NPTS - 1) * BITS + hi * 8);
                bf16x8 fb[4];
#pragma unroll
                for (int ks = 0; ks < 4; ++ks) fb[ks] = __builtin_bit_cast(bf16x8, pB[ks * 2]);

                f32x16 cc;
#pragma unroll
                for (int e = 0; e < 16; ++e) cc[e] = 0.f;
#pragma unroll
                for (int ks = 0; ks < 4; ++ks)
                    cc = __builtin_amdgcn_mfma_f32_32x32x16_bf16(fa[ks], fb[ks], cc, 0, 0, 0);

#pragma unroll
                for (int r = 0; r < 16; ++r) {
                    const bool ok = row_ok[r] && col_ok;
                    float t = cc[r];
                    float u = exp2_fast(fminf(t, 0.f - t));
                    prod *= ok ? (1.0f + u) : 1.0f;
                    st += ok ? t : 0.f;
                    sa += ok ? fabsf(t) : 0.f;
                }
            }
        }
        float ssp = fmaf(st + sa, 0.5f, flog2(prod));
        float stt = st;
#pragma unroll
        for (int d = 32; d > 0; d >>= 1) {
            ssp += __shfl_xor(ssp, d, 64);
            stt += __shfl_xor(stt, d, 64);
        }
        if (lane == 0) { red[wave] = ssp; red[4 + wave] = stt; }
        __syncthreads();
        if (tid == 0) {
            B_sp[q] = (double)red[0] + (double)red[1] + (double)red[2] + (double)red[3];
            B_t[q]  = (double)red[4] + (double)red[5] + (double)red[6] + (double)red[7];
        }
    }
}

// ---------------------------------------------------------------------------
// K4: finalize. Symmetry corrections: S_upper = A_off + (A_diag - Dsp)/2;
// S_same = (B_sp - Dsp)/2; T_same = (B_t - Dt)/2. Weights from histogram.
// ---------------------------------------------------------------------------
__global__ __launch_bounds__(256) void final_kernel(const int* __restrict__ tgt,
                                                    const double* __restrict__ wsP,
                                                    const double* __restrict__ wsD,
                                                    float* __restrict__ out) {
    __shared__ int hist[NCLS];
    __shared__ double r0[256], r1[256], r2[256], r3[256], r4[256], rd[256 * 2];
    const int tid = threadIdx.x;

    const double* A_off = wsP;
    const double* A_dia = (const double*)((const char*)wsP + 16640u);
    const double* C_cls = (const double*)((const char*)wsP + 33280u);
    const double* B_sp  = (const double*)((const char*)wsP + 49664u);
    const double* B_t   = (const double*)((const char*)wsP + 50688u);

    for (int i = tid; i < NCLS; i += 256) hist[i] = 0;
    __syncthreads();
    for (int i = tid; i < NPTS; i += 256) atomicAdd(&hist[tgt[i]], 1);
    __syncthreads();

    double ao = 0.0, ad = 0.0, cl = 0.0, bs = 0.0, bt = 0.0, dsp = 0.0, dt = 0.0;
    for (int i = tid; i < NPAIRS; i += 256) { ao += A_off[i]; ad += A_dia[i]; }
    for (int i = tid; i < NCLSB; i += 256) cl += C_cls[i];
    if (tid < NCLS) { bs = B_sp[tid]; bt = B_t[tid]; }
    if (tid < 64)   { dsp = wsD[tid * 2]; dt = wsD[tid * 2 + 1]; }
    r0[tid] = ao; r1[tid] = ad; r2[tid] = cl; r3[tid] = bs; r4[tid] = bt;
    rd[tid] = dsp; rd[256 + tid] = dt;
    __syncthreads();
    for (int sd = 128; sd > 0; sd >>= 1) {
        if (tid < sd) {
            r0[tid] += r0[tid + sd]; r1[tid] += r1[tid + sd];
            r2[tid] += r2[tid + sd]; r3[tid] += r3[tid + sd];
            r4[tid] += r4[tid + sd];
            rd[tid] += rd[tid + sd]; rd[256 + tid] += rd[256 + tid + sd];
        }
        __syncthreads();
    }

    if (tid == 0) {
        double n_pos = 0.0;
        for (int k = 0; k < NCLS; ++k) {
            double cc = (double)hist[k];
            n_pos += cc * cc;
        }
        const double Nd = (double)NPTS;
        double S1 = n_pos - Nd;
        double S0 = Nd * Nd - n_pos;
        if (S0 == 0.0) S0 = 1.0;
        if (S1 == 0.0) S1 = 1.0;
        const double S = S0 + S1;

        const double Dsp = rd[0], Dt = rd[256];
        const double S_all  = r0[0] + 0.5 * (r1[0] - Dsp);   // upper i<j, log2 units
        const double S_same = 0.5 * (r3[0] - Dsp);
        const double T_same = 0.5 * (r4[0] - Dt);

        const double sum_lower =
            ((S / S0) * (S_all - S_same) + (S / S1) * (S_same - T_same)) * LN2;
        const double count = Nd * (Nd - 1.0) * 0.5;
        const double hash_loss = sum_lower / count;
        const double cls_loss  = r2[0] / Nd;
        const double loss = 1.0 * cls_loss + 0.01 * hash_loss;
        out[0] = (float)hash_loss;
        out[1] = (float)cls_loss;
        out[2] = (float)loss;
    }
}

// ---------------------------------------------------------------------------
extern "C" void kernel_launch(void* const* d_in, const int* in_sizes, int n_in,
                              void* d_out, int out_size, void* d_ws, size_t ws_size,
                              hipStream_t stream) {
    const float* H   = (const float*)d_in[0];
    const float* X   = (const float*)d_in[1];
    const int*   tgt = (const int*)d_in[2];
    float* out = (float*)d_out;

    char* w = (char*)d_ws;
    int*            rnk  = (int*)(w + OFF_RANK);
    int*            base = (int*)(w + OFF_BASE);
    unsigned short* Hb   = (unsigned short*)(w + OFF_HB);
    double*         wsP  = (double*)(w + OFF_SAO);   // partial arrays, contiguous
    double*         wsD  = (double*)(w + OFF_D);

    rank_kernel<<<26, 256, 0, stream>>>(tgt, rnk, base);
    scatter_kernel<<<64, 256, 0, stream>>>(H, rnk, Hb, wsD);
    pass_kernel<<<NPAIRS + NCLS, 256, 0, stream>>>(Hb, X, tgt, base, wsP);
    final_kernel<<<1, 256, 0, stream>>>(tgt, wsP, wsD, out);
}

// Round 12
// 38.993 us; speedup vs baseline: 1.6834x; 1.6834x over previous
//
#include <hip/hip_runtime.h>
#include <math.h>

#define NPTS   8192
#define BITS   64
#define NCLS   101
#define TILE   128
#define NT     (NPTS / TILE)            // 64
#define NPAIRS (NT * (NT + 1) / 2)      // 2080
#define WS_CLS (3 * NPAIRS)
#define SCALE  0.84932184f              // sqrt(0.5*log2 e): acc = t = theta*log2(e)
#define LN2    0.6931471805599453
#define SCH_BITS 1064872494             // (127<<23) - 0.0573*2^23 (mean-zero Schraudolph)

// ws doubles: [0,N) sp_all(log2 units) | [N,2N) sp_same | [2N,3N) t_same | [3N,4N) cls

typedef short    bf16x8   __attribute__((ext_vector_type(8)));
typedef unsigned short ushort8v __attribute__((ext_vector_type(8)));
typedef float    f32x16   __attribute__((ext_vector_type(16)));

__device__ __forceinline__ unsigned short f2bf(float f) {
    unsigned int u = __float_as_uint(f);
    u += 0x7FFFu + ((u >> 16) & 1u);     // RNE (inputs finite)
    return (unsigned short)(u >> 16);
}
__device__ __forceinline__ float flog2(float x) {
    float r; asm("v_log_f32 %0, %1" : "=v"(r) : "v"(x)); return r;
}
__device__ __forceinline__ float exp2_fast(float v) {   // v <= 0, > -126
    int ib = (int)(v * 8388608.0f);
    return __int_as_float(ib + SCH_BITS);
}
__device__ __forceinline__ void tile_map(int p, int& ti, int& tj) {
    float disc = (2.0f * NT + 1.0f) * (2.0f * NT + 1.0f) - 8.0f * (float)p;
    ti = (int)(((2.0f * NT + 1.0f) - sqrtf(disc)) * 0.5f);
    if (ti < 0) ti = 0;
    if (ti >= NT) ti = NT - 1;
    while (ti > 0 && (ti * NT - ti * (ti - 1) / 2) > p) ti--;
    while ((ti + 1) * NT - (ti + 1) * ti / 2 <= p) ti++;
    tj = ti + (p - (ti * NT - ti * (ti - 1) / 2));
}

// ---------------------------------------------------------------------------
// Fused hash tile + cls rows. R10 body with DEEP-MLP STAGING: all 16 float4
// loads issued before any convert/ds_write (one L2 latency instead of ~8).
// ---------------------------------------------------------------------------
__global__ __launch_bounds__(256, 3) void hash_cls_kernel(const float* __restrict__ H,
                                                          const float* __restrict__ X,
                                                          const int* __restrict__ tgt,
                                                          double* __restrict__ ws) {
    __shared__ unsigned short As[TILE * BITS];
    __shared__ unsigned short Bs[TILE * BITS];
    __shared__ int tI[TILE];
    __shared__ int tJ[TILE];
    __shared__ float red[16];

    const int tid = threadIdx.x;
    const int p = blockIdx.x;
    int ti, tj; tile_map(p, ti, tj);
    const int i0 = ti * TILE, j0 = tj * TILE;
    const bool diag = (ti == tj);

    if (tid < TILE) { tI[tid] = tgt[i0 + tid]; tJ[tid] = tgt[j0 + tid]; }

    // ---- staging phase 1: issue ALL 16 global float4 loads (deep MLP) ----
    float4 buf0[8], buf1[8];
#pragma unroll
    for (int it = 0; it < 8; ++it) {
        const int idx  = tid + it * 256;
        const int half = idx >> 10;
        const int lid  = idx & 1023;
        const int row  = lid >> 3;
        const int c    = lid & 7;
        const float* src = H + (size_t)((half ? j0 : i0) + row) * BITS + c * 8;
        buf0[it] = *(const float4*)src;
        buf1[it] = *(const float4*)(src + 4);
    }
    // ---- staging phase 2: convert + swizzled LDS write ----
#pragma unroll
    for (int it = 0; it < 8; ++it) {
        const int idx  = tid + it * 256;
        const int half = idx >> 10;
        const int lid  = idx & 1023;
        const int row  = lid >> 3;
        const int c    = lid & 7;
        ushort8v v;
        v[0] = f2bf(buf0[it].x * SCALE); v[1] = f2bf(buf0[it].y * SCALE);
        v[2] = f2bf(buf0[it].z * SCALE); v[3] = f2bf(buf0[it].w * SCALE);
        v[4] = f2bf(buf1[it].x * SCALE); v[5] = f2bf(buf1[it].y * SCALE);
        v[6] = f2bf(buf1[it].z * SCALE); v[7] = f2bf(buf1[it].w * SCALE);
        unsigned short* dst = half ? Bs : As;
        *(ushort8v*)&dst[row * BITS + ((c ^ (row & 7)) * 8)] = v;
    }
    __syncthreads();

    const int lane = tid & 63, wave = tid >> 6;
    const int wr = wave >> 1, wc = wave & 1;
    const int lrow = lane & 31, hi = lane >> 5;

    f32x16 acc[2][2];
#pragma unroll
    for (int a = 0; a < 2; ++a)
#pragma unroll
        for (int b = 0; b < 2; ++b)
#pragma unroll
            for (int e = 0; e < 16; ++e) acc[a][b][e] = 0.f;

    auto ldfrag = [](const unsigned short* S, int row, int chunk) -> bf16x8 {
        ushort8v r = *(const ushort8v*)&S[row * BITS + ((chunk ^ (row & 7)) * 8)];
        return __builtin_bit_cast(bf16x8, r);
    };

#pragma unroll
    for (int ks = 0; ks < 4; ++ks) {
        const int ch = ks * 2 + hi;
        bf16x8 a0 = ldfrag(As, wr * 64 +      lrow, ch);
        bf16x8 a1 = ldfrag(As, wr * 64 + 32 + lrow, ch);
        bf16x8 b0 = ldfrag(Bs, wc * 64 +      lrow, ch);
        bf16x8 b1 = ldfrag(Bs, wc * 64 + 32 + lrow, ch);
        acc[0][0] = __builtin_amdgcn_mfma_f32_32x32x16_bf16(a0, b0, acc[0][0], 0, 0, 0);
        acc[0][1] = __builtin_amdgcn_mfma_f32_32x32x16_bf16(a0, b1, acc[0][1], 0, 0, 0);
        acc[1][0] = __builtin_amdgcn_mfma_f32_32x32x16_bf16(a1, b0, acc[1][0], 0, 0, 0);
        acc[1][1] = __builtin_amdgcn_mfma_f32_32x32x16_bf16(a1, b1, acc[1][1], 0, 0, 0);
    }

    float prod_all = 1.f, prod_same = 1.f;
    float s_relu = 0.f, s_relu_s = 0.f, t_sum_s = 0.f;

    if (!diag) {
#pragma unroll
        for (int it = 0; it < 2; ++it) {
            int trow[16];
#pragma unroll
            for (int r = 0; r < 16; ++r)
                trow[r] = tI[wr * 64 + it * 32 + (r & 3) + 8 * (r >> 2) + 4 * hi];
#pragma unroll
            for (int jt = 0; jt < 2; ++jt) {
                const int tc = tJ[wc * 64 + jt * 32 + lrow];
                const f32x16& C = it ? (jt ? acc[1][1] : acc[1][0])
                                     : (jt ? acc[0][1] : acc[0][0]);
#pragma unroll
                for (int r = 0; r < 16; ++r) {
                    float t = C[r];                           // theta*log2e
                    float v = fmaxf(fminf(t, 0.f - t), -126.f); // -|t|
                    float u = exp2_fast(v);                   // ~2^{-|t|}
                    float w = 1.0f + u;
                    bool  m = (trow[r] == tc);
                    prod_all  *= w;
                    prod_same *= m ? w : 1.0f;
                    float rl = fmaxf(t, 0.f);
                    s_relu   += rl;
                    s_relu_s += m ? rl : 0.f;
                    t_sum_s  += m ? t  : 0.f;
                }
            }
        }
    } else {
#pragma unroll
        for (int it = 0; it < 2; ++it) {
            int trow[16], lrr[16];
#pragma unroll
            for (int r = 0; r < 16; ++r) {
                lrr[r] = wr * 64 + it * 32 + (r & 3) + 8 * (r >> 2) + 4 * hi;
                trow[r] = tI[lrr[r]];
            }
#pragma unroll
            for (int jt = 0; jt < 2; ++jt) {
                const int lc = wc * 64 + jt * 32 + lrow;
                const int tc = tJ[lc];
                const f32x16& C = it ? (jt ? acc[1][1] : acc[1][0])
                                     : (jt ? acc[0][1] : acc[0][0]);
#pragma unroll
                for (int r = 0; r < 16; ++r) {
                    float t = C[r];
                    float v = fmaxf(fminf(t, 0.f - t), -126.f);
                    float u = exp2_fast(v);
                    float w = 1.0f + u;
                    bool  vd = lc > lrr[r];
                    bool  m  = vd && (trow[r] == tc);
                    prod_all  *= vd ? w : 1.0f;
                    prod_same *= m  ? w : 1.0f;
                    float rl = fmaxf(t, 0.f);
                    s_relu   += vd ? rl : 0.f;
                    s_relu_s += m  ? rl : 0.f;
                    t_sum_s  += m  ? t  : 0.f;
                }
            }
        }
    }

    float s_all  = s_relu   + flog2(prod_all);    // softplus/ln2 totals
    float s_same = s_relu_s + flog2(prod_same);
    float t_same = t_sum_s;

#pragma unroll
    for (int d = 32; d > 0; d >>= 1) {
        s_all  += __shfl_xor(s_all,  d, 64);
        s_same += __shfl_xor(s_same, d, 64);
        t_same += __shfl_xor(t_same, d, 64);
    }
    if (lane == 0) { red[wave] = s_all; red[4 + wave] = s_same; red[8 + wave] = t_same; }

    {   // fused cls rows
        const int row = p * 4 + wave;
        float nll = 0.f;
        if (row < NPTS) {
            const float* x = X + (size_t)row * NCLS;
            float x1 = x[lane];
            float x2 = (lane + 64 < NCLS) ? x[lane + 64] : -INFINITY;
            float m = fmaxf(x1, x2);
#pragma unroll
            for (int d = 32; d > 0; d >>= 1) m = fmaxf(m, __shfl_xor(m, d, 64));
            float e = __expf(x1 - m) + ((lane + 64 < NCLS) ? __expf(x2 - m) : 0.f);
#pragma unroll
            for (int d = 32; d > 0; d >>= 1) e += __shfl_xor(e, d, 64);
            if (lane == 0) nll = m + __logf(e) - x[tgt[row]];
        }
        if (lane == 0) red[12 + wave] = nll;
    }
    __syncthreads();
    if (tid == 0) {
        ws[p]              = (double)red[0]  + (double)red[1]  + (double)red[2]  + (double)red[3];
        ws[NPAIRS + p]     = (double)red[4]  + (double)red[5]  + (double)red[6]  + (double)red[7];
        ws[2 * NPAIRS + p] = (double)red[8]  + (double)red[9]  + (double)red[10] + (double)red[11];
        ws[WS_CLS + p]     = (double)red[12] + (double)red[13] + (double)red[14] + (double)red[15];
    }
}

// ---------------------------------------------------------------------------
// Finalize: histogram -> S0/S1 weights; double reduction; ln2 fold here.
// ---------------------------------------------------------------------------
__global__ __launch_bounds__(256) void final_kernel(const int* __restrict__ tgt,
                                                    const double* __restrict__ ws,
                                                    float* __restrict__ out) {
    __shared__ int hist[NCLS];
    __shared__ double r0[256], r1[256], r2[256], rc[256];
    const int tid = threadIdx.x;

    for (int i = tid; i < NCLS; i += 256) hist[i] = 0;
    __syncthreads();
    for (int i = tid; i < NPTS; i += 256) atomicAdd(&hist[tgt[i]], 1);
    __syncthreads();

    double a = 0.0, s = 0.0, t = 0.0, c = 0.0;
    for (int i = tid; i < NPAIRS; i += 256) {
        a += ws[i];
        s += ws[NPAIRS + i];
        t += ws[2 * NPAIRS + i];
        c += ws[WS_CLS + i];
    }
    r0[tid] = a; r1[tid] = s; r2[tid] = t; rc[tid] = c;
    __syncthreads();
    for (int sdt = 128; sdt > 0; sdt >>= 1) {
        if (tid < sdt) {
            r0[tid] += r0[tid + sdt];
            r1[tid] += r1[tid + sdt];
            r2[tid] += r2[tid + sdt];
            rc[tid] += rc[tid + sdt];
        }
        __syncthreads();
    }

    if (tid == 0) {
        double n_pos = 0.0;
        for (int k = 0; k < NCLS; k++) {
            double cc = (double)hist[k];
            n_pos += cc * cc;
        }
        const double Nd = (double)NPTS;
        double S1 = n_pos - Nd;
        double S0 = Nd * Nd - n_pos;
        if (S0 == 0.0) S0 = 1.0;
        if (S1 == 0.0) S1 = 1.0;
        const double S = S0 + S1;
        // partials in log2 / log2e units -> single ln2 factor here
        const double sum_lower =
            ((S / S0) * (r0[0] - r1[0]) + (S / S1) * (r1[0] - r2[0])) * LN2;
        const double count = Nd * (Nd - 1.0) * 0.5;
        const double hash_loss = sum_lower / count;
        const double cls_loss  = rc[0] / Nd;
        const double loss = 1.0 * cls_loss + 0.01 * hash_loss;
        out[0] = (float)hash_loss;
        out[1] = (float)cls_loss;
        out[2] = (float)loss;
    }
}

// ---------------------------------------------------------------------------
extern "C" void kernel_launch(void* const* d_in, const int* in_sizes, int n_in,
                              void* d_out, int out_size, void* d_ws, size_t ws_size,
                              hipStream_t stream) {
    const float* H   = (const float*)d_in[0];
    const float* X   = (const float*)d_in[1];
    const int*   tgt = (const int*)d_in[2];
    float* out = (float*)d_out;
    double* wsd = (double*)d_ws;

    hash_cls_kernel<<<NPAIRS, 256, 0, stream>>>(H, X, tgt, wsd);
    final_kernel<<<1, 256, 0, stream>>>(tgt, wsd, out);
}